// Round 1
// baseline (935.193 us; speedup 1.0000x reference)
//
#include <hip/hip_runtime.h>
#include <math.h>

#define H 64
#define W 64
#define CIN 128
#define COUT 128
#define BATCH 8
#define NPIX (H*W)      // 4096
#define KTOT (9*CIN)    // 1152

// ---------------------------------------------------------------------------
// Kernel 1: x NCHW -> BHWC so per-(y,x) 128-channel gathers are contiguous.
// LDS-tiled 32c x 64x transpose per (b, y, c-chunk).
// ---------------------------------------------------------------------------
__global__ __launch_bounds__(256) void k_transpose(const float* __restrict__ x,
                                                   float* __restrict__ xb) {
  __shared__ float tile[32][65];  // +1 pad: conflict-free transpose read
  int cg = blockIdx.x;            // c-chunk 0..3
  int y  = blockIdx.y;
  int b  = blockIdx.z;
  int t  = threadIdx.x;
#pragma unroll
  for (int j = 0; j < 8; ++j) {
    int idx = t + j * 256;        // 2048 elements
    int ci = idx >> 6, xi = idx & 63;
    tile[ci][xi] = x[(((b * CIN + cg * 32 + ci) * H + y) * W) + xi];
  }
  __syncthreads();
#pragma unroll
  for (int j = 0; j < 8; ++j) {
    int idx = t + j * 256;
    int xi = idx >> 5, ci = idx & 31;
    xb[((b * H + y) * W + xi) * CIN + cg * 32 + ci] = tile[ci][xi];
  }
}

// ---------------------------------------------------------------------------
// Kernel 2: offset(18ch)+mask(9ch) 3x3 conv, direct.  Thread = (wo, oc),
// block = 64 wo x 4 oc.  x reads coalesced along wo; weights wave-uniform.
// ---------------------------------------------------------------------------
__global__ __launch_bounds__(256) void k_offmask(const float* __restrict__ x,
    const float* __restrict__ w_off, const float* __restrict__ b_off,
    const float* __restrict__ w_mod, const float* __restrict__ b_mod,
    float* __restrict__ cdst) {
  int wo = threadIdx.x;
  int oc = blockIdx.y * 4 + threadIdx.y;
  int ho = blockIdx.x;
  int b  = blockIdx.z;
  if (oc >= 27) return;
  const float* wp;
  float acc;
  if (oc < 18) { wp = w_off + oc * CIN * 9;        acc = b_off[oc]; }
  else         { wp = w_mod + (oc - 18) * CIN * 9; acc = b_mod[oc - 18]; }
  const float* xb0 = x + (size_t)(b * CIN) * NPIX;
  for (int c = 0; c < CIN; ++c) {
    const float* xc = xb0 + c * NPIX;
    const float* wc = wp + c * 9;
#pragma unroll
    for (int kh = 0; kh < 3; ++kh) {
      int yy = ho - 1 + kh;                 // wave-uniform branch
      if (yy < 0 || yy >= H) continue;
      const float* xr = xc + yy * W;
#pragma unroll
      for (int kw = 0; kw < 3; ++kw) {
        int xx = wo - 1 + kw;
        float v = (xx >= 0 && xx < W) ? xr[xx] : 0.0f;
        acc = fmaf(v, wc[kh * 3 + kw], acc);
      }
    }
  }
  cdst[(b * 27 + oc) * NPIX + ho * W + wo] = acc;
}

// ---------------------------------------------------------------------------
// Kernel 3: raw conv channels -> per-(pixel,tap) {py, px, mask} float4 table
// ---------------------------------------------------------------------------
__global__ __launch_bounds__(256) void k_pym(const float* __restrict__ cdst,
                                             float4* __restrict__ pym) {
  int t = blockIdx.x * 256 + threadIdx.x;
  if (t >= BATCH * NPIX * 9) return;
  int tap = t % 9;
  int rem = t / 9;
  int pix = rem % NPIX;
  int b   = rem / NPIX;
  float dy = cdst[(b * 27 + 2 * tap)     * NPIX + pix];
  float dx = cdst[(b * 27 + 2 * tap + 1) * NPIX + pix];
  float z  = cdst[(b * 27 + 18 + tap)    * NPIX + pix];
  float m  = 2.0f / (1.0f + expf(-z));
  int ho = pix >> 6, wo = pix & 63;
  float py = (float)(ho - 1 + tap / 3) + dy;
  float px = (float)(wo - 1 + tap % 3) + dx;
  pym[t] = make_float4(py, px, m, 0.0f);
}

// ---------------------------------------------------------------------------
// Kernel 4: w_reg [oc][c][tap] -> wT[k = tap*128+c][oc]  (coalesced GEMM loads)
// ---------------------------------------------------------------------------
__global__ __launch_bounds__(256) void k_wT(const float* __restrict__ w_reg,
                                            float* __restrict__ wT) {
  int e = blockIdx.x * 256 + threadIdx.x;   // e = k*128 + oc
  int oc = e & 127, k = e >> 7;
  int tap = k >> 7, c = k & 127;
  wT[e] = w_reg[(oc * CIN + c) * 9 + tap];
}

// ---------------------------------------------------------------------------
// Kernel 5: main deformable conv.  Block = 8 pixels, 256 threads.
// Phase 1: bilinear-sample vs[k=tap*128+c][p] into LDS (stride 9: the
//          128-lane c writes hit banks 2-way max = free).
// Phase 2: GEMM 128oc x 1152k x 8px. Thread = (ocg = t&31 -> 4 oc, px = t>>5).
//          Per k: 1 float4 global (wT, L2-resident) + 1 broadcast LDS b32
//          + 4 FMA.
// ---------------------------------------------------------------------------
__global__ __launch_bounds__(256) void k_deform(const float* __restrict__ xb,
    const float4* __restrict__ pym, const float* __restrict__ wT,
    float* __restrict__ out) {
  __shared__ float vs[KTOT * 9];
  __shared__ float4 pq[72];
  int tile = blockIdx.x, b = blockIdx.y;
  int pix0 = tile * 8;
  int t = threadIdx.x;
  if (t < 72) pq[t] = pym[(b * NPIX + pix0 + t / 9) * 9 + (t % 9)];
  __syncthreads();

  int c = t & 127, hh = t >> 7;
  const float* xbase = xb + (size_t)b * NPIX * CIN + c;
  for (int i = hh; i < 72; i += 2) {        // i wave-uniform
    int p = i / 9, tap = i - p * 9;
    float4 q = pq[i];
    float py = q.x, px = q.y, m = q.z;
    float yf = floorf(py), xf = floorf(px);
    float wy = py - yf, wx = px - xf;
    int y0 = (int)yf, x0 = (int)xf;
    int y1 = y0 + 1, x1 = x0 + 1;
    float vy0 = (y0 >= 0 && y0 < H) ? 1.f : 0.f;
    float vy1 = (y1 >= 0 && y1 < H) ? 1.f : 0.f;
    float vx0 = (x0 >= 0 && x0 < W) ? 1.f : 0.f;
    float vx1 = (x1 >= 0 && x1 < W) ? 1.f : 0.f;
    float w00 = (1.f - wy) * (1.f - wx) * m * vy0 * vx0;
    float w01 = (1.f - wy) * wx * m * vy0 * vx1;
    float w10 = wy * (1.f - wx) * m * vy1 * vx0;
    float w11 = wy * wx * m * vy1 * vx1;
    int y0c = min(max(y0, 0), H - 1), y1c = min(max(y1, 0), H - 1);
    int x0c = min(max(x0, 0), W - 1), x1c = min(max(x1, 0), W - 1);
    float v00 = xbase[(y0c * W + x0c) * CIN];
    float v01 = xbase[(y0c * W + x1c) * CIN];
    float v10 = xbase[(y1c * W + x0c) * CIN];
    float v11 = xbase[(y1c * W + x1c) * CIN];
    vs[(tap * 128 + c) * 9 + p] =
        w00 * v00 + w01 * v01 + w10 * v10 + w11 * v11;
  }
  __syncthreads();

  int ocg = t & 31, px = t >> 5;
  const float* wp = wT + ocg * 4;
  float a0 = 0.f, a1 = 0.f, a2 = 0.f, a3 = 0.f;
#pragma unroll 4
  for (int k = 0; k < KTOT; ++k) {
    float4 w4 = *(const float4*)(wp + (size_t)k * 128);
    float sv = vs[k * 9 + px];
    a0 = fmaf(w4.x, sv, a0);
    a1 = fmaf(w4.y, sv, a1);
    a2 = fmaf(w4.z, sv, a2);
    a3 = fmaf(w4.w, sv, a3);
  }
  int pix = pix0 + px;
  float* op = out + ((size_t)b * COUT + ocg * 4) * NPIX + pix;
  op[0] = a0; op[NPIX] = a1; op[2 * NPIX] = a2; op[3 * NPIX] = a3;
}

// ---------------------------------------------------------------------------
extern "C" void kernel_launch(void* const* d_in, const int* in_sizes, int n_in,
                              void* d_out, int out_size, void* d_ws, size_t ws_size,
                              hipStream_t stream) {
  const float* x     = (const float*)d_in[0];
  const float* w_off = (const float*)d_in[1];
  const float* b_off = (const float*)d_in[2];
  const float* w_mod = (const float*)d_in[3];
  const float* b_mod = (const float*)d_in[4];
  const float* w_reg = (const float*)d_in[5];

  float* ws   = (float*)d_ws;
  float* xb   = ws;                        // 4,194,304 floats
  float* cdst = xb + 4194304;              //   884,736 floats
  float* pym  = cdst + 884736;             // 1,179,648 floats (float4 aligned)
  float* wT   = pym + 1179648;             //   147,456 floats
  float* out  = (float*)d_out;

  k_transpose<<<dim3(4, 64, 8), 256, 0, stream>>>(x, xb);
  k_offmask<<<dim3(64, 7, 8), dim3(64, 4), 0, stream>>>(x, w_off, b_off,
                                                        w_mod, b_mod, cdst);
  k_pym<<<dim3((BATCH * NPIX * 9 + 255) / 256), 256, 0, stream>>>(
      cdst, (float4*)pym);
  k_wT<<<dim3(576), 256, 0, stream>>>(w_reg, wT);
  k_deform<<<dim3(NPIX / 8, BATCH), 256, 0, stream>>>(
      xb, (const float4*)pym, wT, out);
}

// Round 3
// 432.019 us; speedup vs baseline: 2.1647x; 2.1647x over previous
//
#include <hip/hip_runtime.h>
#include <math.h>

#define H 64
#define W 64
#define CIN 128
#define COUT 128
#define BATCH 8
#define NPIX (H*W)      // 4096
#define PXT 32          // pixels per k_deform block
#define AP  136         // padded LDS pitch in bf16 elems (136*2B=272B, 2-way banks = free)

typedef __attribute__((ext_vector_type(8))) short bf16x8;
typedef __attribute__((ext_vector_type(4))) float f32x4;

static __device__ inline short f2bf(float f) {
  union { float f; unsigned u; } v; v.f = f;
  unsigned r = v.u + 0x7FFF + ((v.u >> 16) & 1);   // RNE
  return (short)(r >> 16);
}

// ---------------------------------------------------------------------------
// Kernel 1: x NCHW -> BHWC so per-(y,x) 128-channel gathers are contiguous.
// ---------------------------------------------------------------------------
__global__ __launch_bounds__(256) void k_transpose(const float* __restrict__ x,
                                                   float* __restrict__ xb) {
  __shared__ float tile[32][65];
  int cg = blockIdx.x;
  int y  = blockIdx.y;
  int b  = blockIdx.z;
  int t  = threadIdx.x;
#pragma unroll
  for (int j = 0; j < 8; ++j) {
    int idx = t + j * 256;
    int ci = idx >> 6, xi = idx & 63;
    tile[ci][xi] = x[(((b * CIN + cg * 32 + ci) * H + y) * W) + xi];
  }
  __syncthreads();
#pragma unroll
  for (int j = 0; j < 8; ++j) {
    int idx = t + j * 256;
    int xi = idx >> 5, ci = idx & 31;
    xb[((b * H + y) * W + xi) * CIN + cg * 32 + ci] = tile[ci][xi];
  }
}

// ---------------------------------------------------------------------------
// Kernel 2: offset(18ch)+mask(9ch) 3x3 conv, direct (unchanged this round).
// ---------------------------------------------------------------------------
__global__ __launch_bounds__(256) void k_offmask(const float* __restrict__ x,
    const float* __restrict__ w_off, const float* __restrict__ b_off,
    const float* __restrict__ w_mod, const float* __restrict__ b_mod,
    float* __restrict__ cdst) {
  int wo = threadIdx.x;
  int oc = blockIdx.y * 4 + threadIdx.y;
  int ho = blockIdx.x;
  int b  = blockIdx.z;
  if (oc >= 27) return;
  const float* wp;
  float acc;
  if (oc < 18) { wp = w_off + oc * CIN * 9;        acc = b_off[oc]; }
  else         { wp = w_mod + (oc - 18) * CIN * 9; acc = b_mod[oc - 18]; }
  const float* xb0 = x + (size_t)(b * CIN) * NPIX;
  for (int c = 0; c < CIN; ++c) {
    const float* xc = xb0 + c * NPIX;
    const float* wc = wp + c * 9;
#pragma unroll
    for (int kh = 0; kh < 3; ++kh) {
      int yy = ho - 1 + kh;
      if (yy < 0 || yy >= H) continue;
      const float* xr = xc + yy * W;
#pragma unroll
      for (int kw = 0; kw < 3; ++kw) {
        int xx = wo - 1 + kw;
        float v = (xx >= 0 && xx < W) ? xr[xx] : 0.0f;
        acc = fmaf(v, wc[kh * 3 + kw], acc);
      }
    }
  }
  cdst[(b * 27 + oc) * NPIX + ho * W + wo] = acc;
}

// ---------------------------------------------------------------------------
// Kernel 3: conv channels -> per-(pixel,tap) {py, px, mask} float4 table
// ---------------------------------------------------------------------------
__global__ __launch_bounds__(256) void k_pym(const float* __restrict__ cdst,
                                             float4* __restrict__ pym) {
  int t = blockIdx.x * 256 + threadIdx.x;
  if (t >= BATCH * NPIX * 9) return;
  int tap = t % 9;
  int rem = t / 9;
  int pix = rem % NPIX;
  int b   = rem / NPIX;
  float dy = cdst[(b * 27 + 2 * tap)     * NPIX + pix];
  float dx = cdst[(b * 27 + 2 * tap + 1) * NPIX + pix];
  float z  = cdst[(b * 27 + 18 + tap)    * NPIX + pix];
  float m  = 2.0f / (1.0f + expf(-z));
  int ho = pix >> 6, wo = pix & 63;
  float py = (float)(ho - 1 + tap / 3) + dy;
  float px = (float)(wo - 1 + tap % 3) + dx;
  pym[t] = make_float4(py, px, m, 0.0f);
}

// ---------------------------------------------------------------------------
// Kernel 4: w_reg [oc][c][tap] fp32 -> wA[tap][oc][c] bf16
// ---------------------------------------------------------------------------
__global__ __launch_bounds__(256) void k_wAb(const float* __restrict__ w_reg,
                                             short* __restrict__ wA) {
  int e = blockIdx.x * 256 + threadIdx.x;   // e = tap*16384 + oc*128 + c
  int tap = e >> 14, oc = (e >> 7) & 127, cc = e & 127;
  wA[e] = f2bf(w_reg[(oc * 128 + cc) * 9 + tap]);
}

// ---------------------------------------------------------------------------
// Kernel 5: main deformable conv as bf16 MFMA GEMM.
// Block: 32 px x 128 oc, 256 threads (4 waves; wave w -> oc [32w, 32w+32)).
// Per tap (K-chunk = 128 channels):
//   - stage wA[tap] (128oc x 128c bf16, 32 KB) -> LDS (padded pitch 136)
//   - bilinear-sample vs[px][c] bf16 -> LDS
//   - 4 k-steps x 2x2 tile of mfma_f32_16x16x32_bf16
// MFMA layouts (m89/m91/m120): A[m=lane&15][k=quad*8+j],
//   B[k=quad*8+j][n=lane&15], D[m=quad*4+r][n=lane&15].
// ---------------------------------------------------------------------------
__global__ __launch_bounds__(256) void k_deform(const float* __restrict__ xb,
    const float4* __restrict__ pym, const short* __restrict__ wA,
    float* __restrict__ out) {
  __shared__ __align__(16) short wa[128 * AP];   // 34816 B
  __shared__ __align__(16) short vs[PXT * AP];   //  8704 B
  __shared__ float4 pq[PXT * 9];                 //  4608 B

  int tile = blockIdx.x, b = blockIdx.y;
  int pix0 = tile * PXT;
  int t = threadIdx.x;
  int lane = t & 63;
  int wv = t >> 6;
  int l16 = lane & 15, quad = lane >> 4;

  // FIX (R2 bug): 288 entries > 256 threads -> grid-stride, not if(t<288)
  for (int i = t; i < PXT * 9; i += 256)
    pq[i] = pym[(size_t)(b * NPIX + pix0 + i / 9) * 9 + (i % 9)];

  int c = t & 127, half = t >> 7;
  const float* xbase = xb + (size_t)b * NPIX * CIN + c;

  int oc_off = wv * 32;
  f32x4 acc[2][2] = {};

  for (int tap = 0; tap < 9; ++tap) {
    __syncthreads();   // previous tap's LDS fully consumed (and pq visible)

    // --- stage A tile: 2048 chunks of 16B, 8 per thread, coalesced ---
    {
      const float4* src = (const float4*)(wA + (size_t)tap * 128 * 128);
#pragma unroll
      for (int j = 0; j < 8; ++j) {
        int e = t + j * 256;
        int oc = e >> 4, seg = e & 15;
        *(float4*)&wa[oc * AP + seg * 8] = src[e];
      }
    }

    // --- sample B tile: vs[px][c], 16 px per thread ---
#pragma unroll 4
    for (int i = 0; i < 16; ++i) {
      int p = half * 16 + i;
      float4 q = pq[p * 9 + tap];
      float py = q.x, pxx = q.y, m = q.z;
      float yf = floorf(py), xf = floorf(pxx);
      float wy = py - yf, wx = pxx - xf;
      int y0 = (int)yf, x0 = (int)xf;
      int y1 = y0 + 1, x1 = x0 + 1;
      float vy0 = (y0 >= 0 && y0 < H) ? 1.f : 0.f;
      float vy1 = (y1 >= 0 && y1 < H) ? 1.f : 0.f;
      float vx0 = (x0 >= 0 && x0 < W) ? 1.f : 0.f;
      float vx1 = (x1 >= 0 && x1 < W) ? 1.f : 0.f;
      float w00 = (1.f - wy) * (1.f - wx) * m * vy0 * vx0;
      float w01 = (1.f - wy) * wx * m * vy0 * vx1;
      float w10 = wy * (1.f - wx) * m * vy1 * vx0;
      float w11 = wy * wx * m * vy1 * vx1;
      int y0c = min(max(y0, 0), H - 1), y1c = min(max(y1, 0), H - 1);
      int x0c = min(max(x0, 0), W - 1), x1c = min(max(x1, 0), W - 1);
      float v00 = xbase[(y0c * W + x0c) * CIN];
      float v01 = xbase[(y0c * W + x1c) * CIN];
      float v10 = xbase[(y1c * W + x0c) * CIN];
      float v11 = xbase[(y1c * W + x1c) * CIN];
      float val = w00 * v00 + w01 * v01 + w10 * v10 + w11 * v11;
      vs[p * AP + c] = f2bf(val);
    }
    __syncthreads();

    // --- MFMA: 4 k-steps, 2x2 tile ---
#pragma unroll
    for (int kb = 0; kb < 4; ++kb) {
      int kcol = kb * 32 + quad * 8;
      bf16x8 a0 = *(const bf16x8*)&wa[(oc_off + l16) * AP + kcol];
      bf16x8 a1 = *(const bf16x8*)&wa[(oc_off + 16 + l16) * AP + kcol];
      bf16x8 b0 = *(const bf16x8*)&vs[l16 * AP + kcol];
      bf16x8 b1 = *(const bf16x8*)&vs[(16 + l16) * AP + kcol];
      acc[0][0] = __builtin_amdgcn_mfma_f32_16x16x32_bf16(a0, b0, acc[0][0], 0, 0, 0);
      acc[0][1] = __builtin_amdgcn_mfma_f32_16x16x32_bf16(a0, b1, acc[0][1], 0, 0, 0);
      acc[1][0] = __builtin_amdgcn_mfma_f32_16x16x32_bf16(a1, b0, acc[1][0], 0, 0, 0);
      acc[1][1] = __builtin_amdgcn_mfma_f32_16x16x32_bf16(a1, b1, acc[1][1], 0, 0, 0);
    }
  }

  // --- epilogue: D[m][n] -> out[b][oc][pix] ---
#pragma unroll
  for (int mt = 0; mt < 2; ++mt)
#pragma unroll
    for (int nt = 0; nt < 2; ++nt)
#pragma unroll
      for (int r = 0; r < 4; ++r) {
        int oc = oc_off + mt * 16 + quad * 4 + r;
        int px = nt * 16 + l16;
        out[(size_t)(b * COUT + oc) * NPIX + pix0 + px] = acc[mt][nt][r];
      }
}

// ---------------------------------------------------------------------------
extern "C" void kernel_launch(void* const* d_in, const int* in_sizes, int n_in,
                              void* d_out, int out_size, void* d_ws, size_t ws_size,
                              hipStream_t stream) {
  const float* x     = (const float*)d_in[0];
  const float* w_off = (const float*)d_in[1];
  const float* b_off = (const float*)d_in[2];
  const float* w_mod = (const float*)d_in[3];
  const float* b_mod = (const float*)d_in[4];
  const float* w_reg = (const float*)d_in[5];

  float* ws   = (float*)d_ws;
  float* xb   = ws;                        // 4,194,304 floats
  float* cdst = xb + 4194304;              //   884,736 floats
  float* pym  = cdst + 884736;             // 1,179,648 floats (float4 aligned)
  short* wAb  = (short*)(pym + 1179648);   //   147,456 bf16
  float* out  = (float*)d_out;

  k_transpose<<<dim3(4, 64, 8), 256, 0, stream>>>(x, xb);
  k_offmask<<<dim3(64, 7, 8), dim3(64, 4), 0, stream>>>(x, w_off, b_off,
                                                        w_mod, b_mod, cdst);
  k_pym<<<dim3((BATCH * NPIX * 9 + 255) / 256), 256, 0, stream>>>(
      cdst, (float4*)pym);
  k_wAb<<<dim3(576), 256, 0, stream>>>(w_reg, wAb);
  k_deform<<<dim3(NPIX / PXT, BATCH), 256, 0, stream>>>(
      xb, (const float4*)pym, wAb, out);
}

// Round 4
// 179.334 us; speedup vs baseline: 5.2148x; 2.4090x over previous
//
#include <hip/hip_runtime.h>
#include <math.h>

#define H 64
#define W 64
#define CIN 128
#define COUT 128
#define BATCH 8
#define NPIX (H*W)      // 4096
#define PXT 32          // pixels per k_deform block
#define AP  136         // padded LDS pitch in bf16 elems (2-way banks = free, m136)
#define OAP 136         // same pitch for offmask tiles

typedef __attribute__((ext_vector_type(8))) short bf16x8;
typedef __attribute__((ext_vector_type(4))) float f32x4;

static __device__ inline short f2bf(float f) {
  union { float f; unsigned u; } v; v.f = f;
  unsigned r = v.u + 0x7FFF + ((v.u >> 16) & 1);   // RNE
  return (short)(r >> 16);
}

// ---------------------------------------------------------------------------
// Kernel 1: x NCHW -> BHWC, fp32 (for k_deform bilinear) + bf16 (for offmask B)
// ---------------------------------------------------------------------------
__global__ __launch_bounds__(256) void k_transpose(const float* __restrict__ x,
                                                   float* __restrict__ xb,
                                                   short* __restrict__ xbh) {
  __shared__ float tile[32][65];
  int cg = blockIdx.x;
  int y  = blockIdx.y;
  int b  = blockIdx.z;
  int t  = threadIdx.x;
#pragma unroll
  for (int j = 0; j < 8; ++j) {
    int idx = t + j * 256;
    int ci = idx >> 6, xi = idx & 63;
    tile[ci][xi] = x[(((b * CIN + cg * 32 + ci) * H + y) * W) + xi];
  }
  __syncthreads();
#pragma unroll
  for (int j = 0; j < 8; ++j) {
    int idx = t + j * 256;
    int xi = idx >> 5, ci = idx & 31;
    float v = tile[ci][xi];
    int o = ((b * H + y) * W + xi) * CIN + cg * 32 + ci;
    xb[o] = v;
    xbh[o] = f2bf(v);
  }
}

// ---------------------------------------------------------------------------
// Kernel 2a: pack w_off(18ch)+w_mod(9ch) -> wOM[tap][oc(32, zero-pad)][c] bf16
// ---------------------------------------------------------------------------
__global__ __launch_bounds__(256) void k_wOffb(const float* __restrict__ w_off,
                                               const float* __restrict__ w_mod,
                                               short* __restrict__ wOM) {
  int e = blockIdx.x * 256 + threadIdx.x;   // e = tap*4096 + oc*128 + c (36864)
  int tap = e >> 12, oc = (e >> 7) & 31, c = e & 127;
  float v = 0.f;
  if (oc < 18)      v = w_off[(oc * 128 + c) * 9 + tap];
  else if (oc < 27) v = w_mod[((oc - 18) * 128 + c) * 9 + tap];
  wOM[e] = f2bf(v);
}

// ---------------------------------------------------------------------------
// Kernel 2b: offset+mask conv as bf16 MFMA GEMM, pym fused into epilogue.
// Block: 128 px x 32 oc, 256 threads (4 waves; wave wv -> px [32wv,32wv+32)).
// Per tap: stage wOM[tap] (32x128 bf16) + im2col B tile (128px x 128c bf16,
// pure bf16x8 copies from xbh), then 4 k-steps x 2x2 MFMA.
// Epilogue: D -> LDS sc[oc][px] -> {py,px,mask} float4 table (k_pym fused).
// ---------------------------------------------------------------------------
__global__ __launch_bounds__(256) void k_offmask(const short* __restrict__ xbh,
    const short* __restrict__ wOM, const float* __restrict__ b_off,
    const float* __restrict__ b_mod, float4* __restrict__ pym) {
  __shared__ __align__(16) short wa_s[32 * OAP];   //  8704 B
  __shared__ __align__(16) short vs[128 * OAP];    // 34816 B
  __shared__ float sc[32 * 132];                   // 16896 B

  int tile = blockIdx.x, b = blockIdx.y;
  int pix0 = tile * 128;
  int t = threadIdx.x;
  int lane = t & 63, wv = t >> 6;
  int l16 = lane & 15, quad = lane >> 4;
  int cg = t & 15, pj = t >> 4;

  const short* xbb = xbh + (size_t)b * NPIX * CIN;
  f32x4 acc[2][2] = {};

  for (int tap = 0; tap < 9; ++tap) {
    __syncthreads();
    // --- stage A: 512 16B chunks, 2 per thread ---
    {
      const float4* src = (const float4*)(wOM + tap * 4096);
#pragma unroll
      for (int j = 0; j < 2; ++j) {
        int e = t + j * 256;
        int oc = e >> 4, seg = e & 15;
        *(float4*)&wa_s[oc * OAP + seg * 8] = src[e];
      }
    }
    // --- stage B: im2col, 8 px per thread, 16B vector copies ---
    int dy = tap / 3 - 1, dx = tap % 3 - 1;
#pragma unroll
    for (int i = 0; i < 8; ++i) {
      int p = pj + i * 16;
      int gp = pix0 + p;
      int y = (gp >> 6) + dy, x = (gp & 63) + dx;
      bf16x8 v = {};
      if (y >= 0 && y < H && x >= 0 && x < W)
        v = *(const bf16x8*)&xbb[(size_t)((y << 6) + x) * CIN + cg * 8];
      *(bf16x8*)&vs[p * OAP + cg * 8] = v;
    }
    __syncthreads();
    // --- MFMA: 4 k-steps, 2x2 tile (M=32 oc, N=32 px per wave) ---
#pragma unroll
    for (int kb = 0; kb < 4; ++kb) {
      int kcol = kb * 32 + quad * 8;
      bf16x8 a0 = *(const bf16x8*)&wa_s[l16 * OAP + kcol];
      bf16x8 a1 = *(const bf16x8*)&wa_s[(16 + l16) * OAP + kcol];
      bf16x8 b0 = *(const bf16x8*)&vs[(wv * 32 + l16) * OAP + kcol];
      bf16x8 b1 = *(const bf16x8*)&vs[(wv * 32 + 16 + l16) * OAP + kcol];
      acc[0][0] = __builtin_amdgcn_mfma_f32_16x16x32_bf16(a0, b0, acc[0][0], 0, 0, 0);
      acc[0][1] = __builtin_amdgcn_mfma_f32_16x16x32_bf16(a0, b1, acc[0][1], 0, 0, 0);
      acc[1][0] = __builtin_amdgcn_mfma_f32_16x16x32_bf16(a1, b0, acc[1][0], 0, 0, 0);
      acc[1][1] = __builtin_amdgcn_mfma_f32_16x16x32_bf16(a1, b1, acc[1][1], 0, 0, 0);
    }
  }
  __syncthreads();
  // --- D[m][n] -> sc[oc][px] (pitch 132: 2-way banks = free) ---
#pragma unroll
  for (int mt = 0; mt < 2; ++mt)
#pragma unroll
    for (int nt = 0; nt < 2; ++nt)
#pragma unroll
      for (int r = 0; r < 4; ++r) {
        int oc = mt * 16 + quad * 4 + r;
        int p  = wv * 32 + nt * 16 + l16;
        sc[oc * 132 + p] = acc[mt][nt][r];
      }
  __syncthreads();
  // --- fused k_pym: 1152 entries, grid-stride ---
  for (int i = t; i < 128 * 9; i += 256) {
    int tap = i % 9, p = i / 9;
    float dyv = sc[(2 * tap) * 132 + p] + b_off[2 * tap];
    float dxv = sc[(2 * tap + 1) * 132 + p] + b_off[2 * tap + 1];
    float z   = sc[(18 + tap) * 132 + p] + b_mod[tap];
    float m = 2.f / (1.f + expf(-z));
    int gp = pix0 + p;
    float py = (float)((gp >> 6) - 1 + tap / 3) + dyv;
    float px = (float)((gp & 63) - 1 + tap % 3) + dxv;
    pym[(size_t)(b * NPIX + gp) * 9 + tap] = make_float4(py, px, m, 0.f);
  }
}

// ---------------------------------------------------------------------------
// Kernel 4: w_reg [oc][c][tap] fp32 -> wA[tap][oc][c] bf16
// ---------------------------------------------------------------------------
__global__ __launch_bounds__(256) void k_wAb(const float* __restrict__ w_reg,
                                             short* __restrict__ wA) {
  int e = blockIdx.x * 256 + threadIdx.x;   // e = tap*16384 + oc*128 + c
  int tap = e >> 14, oc = (e >> 7) & 127, cc = e & 127;
  wA[e] = f2bf(w_reg[(oc * 128 + cc) * 9 + tap]);
}

// ---------------------------------------------------------------------------
// Kernel 5: main deformable conv as bf16 MFMA GEMM (unchanged from R3).
// ---------------------------------------------------------------------------
__global__ __launch_bounds__(256) void k_deform(const float* __restrict__ xb,
    const float4* __restrict__ pym, const short* __restrict__ wA,
    float* __restrict__ out) {
  __shared__ __align__(16) short wa[128 * AP];   // 34816 B
  __shared__ __align__(16) short vs[PXT * AP];   //  8704 B
  __shared__ float4 pq[PXT * 9];                 //  4608 B

  int tile = blockIdx.x, b = blockIdx.y;
  int pix0 = tile * PXT;
  int t = threadIdx.x;
  int lane = t & 63;
  int wv = t >> 6;
  int l16 = lane & 15, quad = lane >> 4;

  for (int i = t; i < PXT * 9; i += 256)
    pq[i] = pym[(size_t)(b * NPIX + pix0 + i / 9) * 9 + (i % 9)];

  int c = t & 127, half = t >> 7;
  const float* xbase = xb + (size_t)b * NPIX * CIN + c;

  int oc_off = wv * 32;
  f32x4 acc[2][2] = {};

  for (int tap = 0; tap < 9; ++tap) {
    __syncthreads();

    {
      const float4* src = (const float4*)(wA + (size_t)tap * 128 * 128);
#pragma unroll
      for (int j = 0; j < 8; ++j) {
        int e = t + j * 256;
        int oc = e >> 4, seg = e & 15;
        *(float4*)&wa[oc * AP + seg * 8] = src[e];
      }
    }

#pragma unroll 4
    for (int i = 0; i < 16; ++i) {
      int p = half * 16 + i;
      float4 q = pq[p * 9 + tap];
      float py = q.x, pxx = q.y, m = q.z;
      float yf = floorf(py), xf = floorf(pxx);
      float wy = py - yf, wx = pxx - xf;
      int y0 = (int)yf, x0 = (int)xf;
      int y1 = y0 + 1, x1 = x0 + 1;
      float vy0 = (y0 >= 0 && y0 < H) ? 1.f : 0.f;
      float vy1 = (y1 >= 0 && y1 < H) ? 1.f : 0.f;
      float vx0 = (x0 >= 0 && x0 < W) ? 1.f : 0.f;
      float vx1 = (x1 >= 0 && x1 < W) ? 1.f : 0.f;
      float w00 = (1.f - wy) * (1.f - wx) * m * vy0 * vx0;
      float w01 = (1.f - wy) * wx * m * vy0 * vx1;
      float w10 = wy * (1.f - wx) * m * vy1 * vx0;
      float w11 = wy * wx * m * vy1 * vx1;
      int y0c = min(max(y0, 0), H - 1), y1c = min(max(y1, 0), H - 1);
      int x0c = min(max(x0, 0), W - 1), x1c = min(max(x1, 0), W - 1);
      float v00 = xbase[(y0c * W + x0c) * CIN];
      float v01 = xbase[(y0c * W + x1c) * CIN];
      float v10 = xbase[(y1c * W + x0c) * CIN];
      float v11 = xbase[(y1c * W + x1c) * CIN];
      float val = w00 * v00 + w01 * v01 + w10 * v10 + w11 * v11;
      vs[p * AP + c] = f2bf(val);
    }
    __syncthreads();

#pragma unroll
    for (int kb = 0; kb < 4; ++kb) {
      int kcol = kb * 32 + quad * 8;
      bf16x8 a0 = *(const bf16x8*)&wa[(oc_off + l16) * AP + kcol];
      bf16x8 a1 = *(const bf16x8*)&wa[(oc_off + 16 + l16) * AP + kcol];
      bf16x8 b0 = *(const bf16x8*)&vs[l16 * AP + kcol];
      bf16x8 b1 = *(const bf16x8*)&vs[(16 + l16) * AP + kcol];
      acc[0][0] = __builtin_amdgcn_mfma_f32_16x16x32_bf16(a0, b0, acc[0][0], 0, 0, 0);
      acc[0][1] = __builtin_amdgcn_mfma_f32_16x16x32_bf16(a0, b1, acc[0][1], 0, 0, 0);
      acc[1][0] = __builtin_amdgcn_mfma_f32_16x16x32_bf16(a1, b0, acc[1][0], 0, 0, 0);
      acc[1][1] = __builtin_amdgcn_mfma_f32_16x16x32_bf16(a1, b1, acc[1][1], 0, 0, 0);
    }
  }

#pragma unroll
  for (int mt = 0; mt < 2; ++mt)
#pragma unroll
    for (int nt = 0; nt < 2; ++nt)
#pragma unroll
      for (int r = 0; r < 4; ++r) {
        int oc = oc_off + mt * 16 + quad * 4 + r;
        int px = nt * 16 + l16;
        out[(size_t)(b * COUT + oc) * NPIX + pix0 + px] = acc[mt][nt][r];
      }
}

// ---------------------------------------------------------------------------
extern "C" void kernel_launch(void* const* d_in, const int* in_sizes, int n_in,
                              void* d_out, int out_size, void* d_ws, size_t ws_size,
                              hipStream_t stream) {
  const float* x     = (const float*)d_in[0];
  const float* w_off = (const float*)d_in[1];
  const float* b_off = (const float*)d_in[2];
  const float* w_mod = (const float*)d_in[3];
  const float* b_mod = (const float*)d_in[4];
  const float* w_reg = (const float*)d_in[5];

  float* ws   = (float*)d_ws;
  float* xb   = ws;                        // 4,194,304 f32 (16 MB)
  float* pym  = xb + 4194304;              // 1,179,648 f32 (float4 entries)
  short* wAb  = (short*)(pym + 1179648);   //   147,456 bf16
  short* xbh  = wAb + 147456;              // 4,194,304 bf16 (8 MB)
  short* wOM  = xbh + 4194304;             //    36,864 bf16
  float* out  = (float*)d_out;

  k_transpose<<<dim3(4, 64, 8), 256, 0, stream>>>(x, xb, xbh);
  k_wOffb<<<dim3(144), 256, 0, stream>>>(w_off, w_mod, wOM);
  k_wAb<<<dim3(576), 256, 0, stream>>>(w_reg, wAb);
  k_offmask<<<dim3(NPIX / 128, BATCH), 256, 0, stream>>>(
      xbh, wOM, b_off, b_mod, (float4*)pym);
  k_deform<<<dim3(NPIX / PXT, BATCH), 256, 0, stream>>>(
      xb, (const float4*)pym, wAb, out);
}

// Round 5
// 152.824 us; speedup vs baseline: 6.1194x; 1.1735x over previous
//
#include <hip/hip_runtime.h>
#include <math.h>

#define H 64
#define W 64
#define CIN 128
#define COUT 128
#define BATCH 8
#define NPIX (H*W)      // 4096
#define PXT 32          // pixels per k_deform block
#define AP  136         // padded LDS pitch in bf16 elems (2-way banks = free, m136)
#define OAP 136

typedef __attribute__((ext_vector_type(8))) short bf16x8;
typedef __attribute__((ext_vector_type(4))) float f32x4;

static __device__ inline short f2bf(float f) {
  union { float f; unsigned u; } v; v.f = f;
  unsigned r = v.u + 0x7FFF + ((v.u >> 16) & 1);   // RNE
  return (short)(r >> 16);
}

// ---------------------------------------------------------------------------
// Kernel 1: x NCHW -> BHWC, fp32 (k_deform bilinear) + bf16 (offmask B)
// ---------------------------------------------------------------------------
__global__ __launch_bounds__(256) void k_transpose(const float* __restrict__ x,
                                                   float* __restrict__ xb,
                                                   short* __restrict__ xbh) {
  __shared__ float tile[32][65];
  int cg = blockIdx.x;
  int y  = blockIdx.y;
  int b  = blockIdx.z;
  int t  = threadIdx.x;
#pragma unroll
  for (int j = 0; j < 8; ++j) {
    int idx = t + j * 256;
    int ci = idx >> 6, xi = idx & 63;
    tile[ci][xi] = x[(((b * CIN + cg * 32 + ci) * H + y) * W) + xi];
  }
  __syncthreads();
#pragma unroll
  for (int j = 0; j < 8; ++j) {
    int idx = t + j * 256;
    int xi = idx >> 5, ci = idx & 31;
    float v = tile[ci][xi];
    int o = ((b * H + y) * W + xi) * CIN + cg * 32 + ci;
    xb[o] = v;
    xbh[o] = f2bf(v);
  }
}

// ---------------------------------------------------------------------------
// Kernel 2a: pack w_off(18)+w_mod(9) -> wOM[tap][oc(32 pad)][c] bf16
// ---------------------------------------------------------------------------
__global__ __launch_bounds__(256) void k_wOffb(const float* __restrict__ w_off,
                                               const float* __restrict__ w_mod,
                                               short* __restrict__ wOM) {
  int e = blockIdx.x * 256 + threadIdx.x;
  int tap = e >> 12, oc = (e >> 7) & 31, c = e & 127;
  float v = 0.f;
  if (oc < 18)      v = w_off[(oc * 128 + c) * 9 + tap];
  else if (oc < 27) v = w_mod[((oc - 18) * 128 + c) * 9 + tap];
  wOM[e] = f2bf(v);
}

// ---------------------------------------------------------------------------
// Kernel 2b: offset+mask conv as bf16 MFMA GEMM + fused pym epilogue.
// (unchanged from R4 — was <83 us; revisit if counters flag it)
// ---------------------------------------------------------------------------
__global__ __launch_bounds__(256) void k_offmask(const short* __restrict__ xbh,
    const short* __restrict__ wOM, const float* __restrict__ b_off,
    const float* __restrict__ b_mod, float4* __restrict__ pym) {
  __shared__ __align__(16) short wa_s[32 * OAP];
  __shared__ __align__(16) short vs[128 * OAP];
  __shared__ float sc[32 * 132];

  int tile = blockIdx.x, b = blockIdx.y;
  int pix0 = tile * 128;
  int t = threadIdx.x;
  int lane = t & 63, wv = t >> 6;
  int l16 = lane & 15, quad = lane >> 4;
  int cg = t & 15, pj = t >> 4;

  const short* xbb = xbh + (size_t)b * NPIX * CIN;
  f32x4 acc[2][2] = {};

  for (int tap = 0; tap < 9; ++tap) {
    __syncthreads();
    {
      const float4* src = (const float4*)(wOM + tap * 4096);
#pragma unroll
      for (int j = 0; j < 2; ++j) {
        int e = t + j * 256;
        int oc = e >> 4, seg = e & 15;
        *(float4*)&wa_s[oc * OAP + seg * 8] = src[e];
      }
    }
    int dy = tap / 3 - 1, dx = tap % 3 - 1;
#pragma unroll
    for (int i = 0; i < 8; ++i) {
      int p = pj + i * 16;
      int gp = pix0 + p;
      int y = (gp >> 6) + dy, x = (gp & 63) + dx;
      bf16x8 v = {};
      if (y >= 0 && y < H && x >= 0 && x < W)
        v = *(const bf16x8*)&xbb[(size_t)((y << 6) + x) * CIN + cg * 8];
      *(bf16x8*)&vs[p * OAP + cg * 8] = v;
    }
    __syncthreads();
#pragma unroll
    for (int kb = 0; kb < 4; ++kb) {
      int kcol = kb * 32 + quad * 8;
      bf16x8 a0 = *(const bf16x8*)&wa_s[l16 * OAP + kcol];
      bf16x8 a1 = *(const bf16x8*)&wa_s[(16 + l16) * OAP + kcol];
      bf16x8 b0 = *(const bf16x8*)&vs[(wv * 32 + l16) * OAP + kcol];
      bf16x8 b1 = *(const bf16x8*)&vs[(wv * 32 + 16 + l16) * OAP + kcol];
      acc[0][0] = __builtin_amdgcn_mfma_f32_16x16x32_bf16(a0, b0, acc[0][0], 0, 0, 0);
      acc[0][1] = __builtin_amdgcn_mfma_f32_16x16x32_bf16(a0, b1, acc[0][1], 0, 0, 0);
      acc[1][0] = __builtin_amdgcn_mfma_f32_16x16x32_bf16(a1, b0, acc[1][0], 0, 0, 0);
      acc[1][1] = __builtin_amdgcn_mfma_f32_16x16x32_bf16(a1, b1, acc[1][1], 0, 0, 0);
    }
  }
  __syncthreads();
#pragma unroll
  for (int mt = 0; mt < 2; ++mt)
#pragma unroll
    for (int nt = 0; nt < 2; ++nt)
#pragma unroll
      for (int r = 0; r < 4; ++r) {
        int oc = mt * 16 + quad * 4 + r;
        int p  = wv * 32 + nt * 16 + l16;
        sc[oc * 132 + p] = acc[mt][nt][r];
      }
  __syncthreads();
  for (int i = t; i < 128 * 9; i += 256) {
    int tap = i % 9, p = i / 9;
    float dyv = sc[(2 * tap) * 132 + p] + b_off[2 * tap];
    float dxv = sc[(2 * tap + 1) * 132 + p] + b_off[2 * tap + 1];
    float z   = sc[(18 + tap) * 132 + p] + b_mod[tap];
    float m = 2.f / (1.f + expf(-z));
    int gp = pix0 + p;
    float py = (float)((gp >> 6) - 1 + tap / 3) + dyv;
    float px = (float)((gp & 63) - 1 + tap % 3) + dxv;
    pym[(size_t)(b * NPIX + gp) * 9 + tap] = make_float4(py, px, m, 0.f);
  }
}

// ---------------------------------------------------------------------------
// Kernel 4: w_reg [oc][c][tap] fp32 -> wave-swizzled bf16 A table.
// Chunk (tap, kb, g): 16 oc-rows (g = oc/16) x 32 k; element (l16, quad, j)
// stored at chunk*512 + (quad*16+l16)*8 + j  ->  one wave A-frag load =
// contiguous 1 KB global_load_dwordx4.
// ---------------------------------------------------------------------------
__global__ __launch_bounds__(256) void k_wAb(const float* __restrict__ w_reg,
                                             short* __restrict__ wAs) {
  int e = blockIdx.x * 256 + threadIdx.x;   // e = tap*16384 + oc*128 + c
  int tap = e >> 14, oc = (e >> 7) & 127, c = e & 127;
  int kb = c >> 5, quad = (c >> 3) & 3, j = c & 7;
  int g = oc >> 4, l16 = oc & 15;
  int out = ((tap * 4 + kb) * 8 + g) * 512 + (quad * 16 + l16) * 8 + j;
  wAs[out] = f2bf(w_reg[(oc * 128 + c) * 9 + tap]);
}

// ---------------------------------------------------------------------------
// Kernel 5: main deformable conv, bf16 MFMA GEMM.
// R5 changes: (1) per-(px,tap) weights+offsets hoisted to LDS once per block
// (wave-uniform broadcast + readfirstlane scalar base -> ~8 VALU/sample);
// (2) A-frags loaded directly from L2-resident swizzled global table (no wa
// LDS, no staging writes); LDS 48.1 -> 17.9 KB.
// ---------------------------------------------------------------------------
__global__ __launch_bounds__(256) void k_deform(const float* __restrict__ xb,
    const float4* __restrict__ pym, const short* __restrict__ wAs,
    float* __restrict__ out) {
  __shared__ __align__(16) short vs[PXT * AP];   //  8704 B
  __shared__ __align__(16) float pw[PXT * 9 * 4]; // 4608 B  {w00,w01,w10,w11}
  __shared__ __align__(16) int   pa[PXT * 9 * 4]; // 4608 B  {a00,a01,a10,a11}

  int tile = blockIdx.x, b = blockIdx.y;
  int pix0 = tile * PXT;
  int t = threadIdx.x;
  int lane = t & 63;
  int wv = t >> 6;
  int l16 = lane & 15, quad = lane >> 4;

  // --- per-(px,tap) precompute: 288 entries, once per block ---
  for (int i = t; i < PXT * 9; i += 256) {
    float4 q = pym[(size_t)(b * NPIX + pix0 + i / 9) * 9 + (i % 9)];
    float py = q.x, pxx = q.y, m = q.z;
    float yf = floorf(py), xf = floorf(pxx);
    float wy = py - yf, wx = pxx - xf;
    int y0 = (int)yf, x0 = (int)xf;
    int y1 = y0 + 1, x1 = x0 + 1;
    float vy0 = (y0 >= 0 && y0 < H) ? 1.f : 0.f;
    float vy1 = (y1 >= 0 && y1 < H) ? 1.f : 0.f;
    float vx0 = (x0 >= 0 && x0 < W) ? 1.f : 0.f;
    float vx1 = (x1 >= 0 && x1 < W) ? 1.f : 0.f;
    int y0c = min(max(y0, 0), H - 1), y1c = min(max(y1, 0), H - 1);
    int x0c = min(max(x0, 0), W - 1), x1c = min(max(x1, 0), W - 1);
    *(float4*)&pw[i * 4] = make_float4((1.f - wy) * (1.f - wx) * m * vy0 * vx0,
                                       (1.f - wy) * wx * m * vy0 * vx1,
                                       wy * (1.f - wx) * m * vy1 * vx0,
                                       wy * wx * m * vy1 * vx1);
    *(int4*)&pa[i * 4] = make_int4(((y0c << 6) + x0c) << 7,
                                   ((y0c << 6) + x1c) << 7,
                                   ((y1c << 6) + x0c) << 7,
                                   ((y1c << 6) + x1c) << 7);
  }

  int c = t & 127, half = t >> 7;
  const float* xbB = xb + (size_t)b * NPIX * CIN;   // uniform base

  f32x4 acc[2][2] = {};

  for (int tap = 0; tap < 9; ++tap) {
    __syncthreads();   // prev tap's vs consumed (tap0: pw/pa visible)

    // --- sample B tile: vs[px][c]; p wave-uniform per iteration ---
#pragma unroll 4
    for (int i = 0; i < 16; ++i) {
      int p = half * 16 + i;
      int idx = (p * 9 + tap) * 4;
      float4 wq = *(const float4*)&pw[idx];
      int a00 = __builtin_amdgcn_readfirstlane(pa[idx]);
      int a01 = __builtin_amdgcn_readfirstlane(pa[idx + 1]);
      int a10 = __builtin_amdgcn_readfirstlane(pa[idx + 2]);
      int a11 = __builtin_amdgcn_readfirstlane(pa[idx + 3]);
      float v00 = xbB[a00 + c];
      float v01 = xbB[a01 + c];
      float v10 = xbB[a10 + c];
      float v11 = xbB[a11 + c];
      float val = wq.x * v00;
      val = fmaf(wq.y, v01, val);
      val = fmaf(wq.z, v10, val);
      val = fmaf(wq.w, v11, val);
      vs[p * AP + c] = f2bf(val);
    }

    // --- A frags direct from global (contiguous 1 KB per wave-load) ---
    const short* wtap = wAs + tap * 16384;
    bf16x8 af0[4], af1[4];
#pragma unroll
    for (int kb = 0; kb < 4; ++kb) {
      af0[kb] = *(const bf16x8*)&wtap[(kb * 8 + wv * 2) * 512 + lane * 8];
      af1[kb] = *(const bf16x8*)&wtap[(kb * 8 + wv * 2 + 1) * 512 + lane * 8];
    }
    __syncthreads();

#pragma unroll
    for (int kb = 0; kb < 4; ++kb) {
      int kcol = kb * 32 + quad * 8;
      bf16x8 b0 = *(const bf16x8*)&vs[l16 * AP + kcol];
      bf16x8 b1 = *(const bf16x8*)&vs[(16 + l16) * AP + kcol];
      acc[0][0] = __builtin_amdgcn_mfma_f32_16x16x32_bf16(af0[kb], b0, acc[0][0], 0, 0, 0);
      acc[0][1] = __builtin_amdgcn_mfma_f32_16x16x32_bf16(af0[kb], b1, acc[0][1], 0, 0, 0);
      acc[1][0] = __builtin_amdgcn_mfma_f32_16x16x32_bf16(af1[kb], b0, acc[1][0], 0, 0, 0);
      acc[1][1] = __builtin_amdgcn_mfma_f32_16x16x32_bf16(af1[kb], b1, acc[1][1], 0, 0, 0);
    }
  }

  // --- epilogue: D[m=quad*4+r][n=l16] -> out[b][oc][pix] ---
  int oc_off = wv * 32;
#pragma unroll
  for (int mt = 0; mt < 2; ++mt)
#pragma unroll
    for (int nt = 0; nt < 2; ++nt)
#pragma unroll
      for (int r = 0; r < 4; ++r) {
        int oc = oc_off + mt * 16 + quad * 4 + r;
        int px = nt * 16 + l16;
        out[(size_t)(b * COUT + oc) * NPIX + pix0 + px] = acc[mt][nt][r];
      }
}

// ---------------------------------------------------------------------------
extern "C" void kernel_launch(void* const* d_in, const int* in_sizes, int n_in,
                              void* d_out, int out_size, void* d_ws, size_t ws_size,
                              hipStream_t stream) {
  const float* x     = (const float*)d_in[0];
  const float* w_off = (const float*)d_in[1];
  const float* b_off = (const float*)d_in[2];
  const float* w_mod = (const float*)d_in[3];
  const float* b_mod = (const float*)d_in[4];
  const float* w_reg = (const float*)d_in[5];

  float* ws   = (float*)d_ws;
  float* xb   = ws;                        // 4,194,304 f32
  float* pym  = xb + 4194304;              // 1,179,648 f32 (float4 entries)
  short* wAs  = (short*)(pym + 1179648);   //   147,456 bf16 (swizzled)
  short* xbh  = wAs + 147456;              // 4,194,304 bf16
  short* wOM  = xbh + 4194304;             //    36,864 bf16
  float* out  = (float*)d_out;

  k_transpose<<<dim3(4, 64, 8), 256, 0, stream>>>(x, xb, xbh);
  k_wOffb<<<dim3(144), 256, 0, stream>>>(w_off, w_mod, wOM);
  k_wAb<<<dim3(576), 256, 0, stream>>>(w_reg, wAs);
  k_offmask<<<dim3(NPIX / 128, BATCH), 256, 0, stream>>>(
      xbh, wOM, b_off, b_mod, (float4*)pym);
  k_deform<<<dim3(NPIX / PXT, BATCH), 256, 0, stream>>>(
      xb, (const float4*)pym, wAs, out);
}

// Round 6
// 147.589 us; speedup vs baseline: 6.3365x; 1.0355x over previous
//
#include <hip/hip_runtime.h>
#include <hip/hip_bf16.h>
#include <math.h>

#define H 64
#define W 64
#define CIN 128
#define COUT 128
#define BATCH 8
#define NPIX (H*W)      // 4096
#define PXT 32          // pixels per k_deform block
#define AP  136         // padded LDS pitch in bf16 elems (2-way banks = free, m136)
#define OAP 136

typedef __attribute__((ext_vector_type(8))) short bf16x8;
typedef __attribute__((ext_vector_type(4))) float f32x4;

static __device__ inline short f2bf(float f) {
  union { float f; unsigned u; } v; v.f = f;
  unsigned r = v.u + 0x7FFF + ((v.u >> 16) & 1);   // RNE
  return (short)(r >> 16);
}

// ---------------------------------------------------------------------------
// Kernel 1 (fused prep): [0,2048) transpose NCHW->BHWC fp32+bf16;
// [2048,2192) pack wOM; [2192,2768) pack swizzled wAs.
// ---------------------------------------------------------------------------
__global__ __launch_bounds__(256) void k_prep(const float* __restrict__ x,
    float* __restrict__ xb, short* __restrict__ xbh,
    const float* __restrict__ w_off, const float* __restrict__ w_mod,
    short* __restrict__ wOM, const float* __restrict__ w_reg,
    short* __restrict__ wAs) {
  __shared__ float tile[32][65];
  int blk = blockIdx.x;
  int t = threadIdx.x;
  if (blk < 2048) {                       // --- transpose ---
    int cg = blk & 3, y = (blk >> 2) & 63, b = blk >> 8;
#pragma unroll
    for (int j = 0; j < 8; ++j) {
      int idx = t + j * 256;
      int ci = idx >> 6, xi = idx & 63;
      tile[ci][xi] = x[(((b * CIN + cg * 32 + ci) * H + y) * W) + xi];
    }
    __syncthreads();
#pragma unroll
    for (int j = 0; j < 8; ++j) {
      int idx = t + j * 256;
      int xi = idx >> 5, ci = idx & 31;
      float v = tile[ci][xi];
      int o = ((b * H + y) * W + xi) * CIN + cg * 32 + ci;
      xb[o] = v;
      xbh[o] = f2bf(v);
    }
  } else if (blk < 2048 + 144) {          // --- wOM pack ---
    int e = (blk - 2048) * 256 + t;       // tap*4096 + oc*128 + c
    int tap = e >> 12, oc = (e >> 7) & 31, c = e & 127;
    float v = 0.f;
    if (oc < 18)      v = w_off[(oc * 128 + c) * 9 + tap];
    else if (oc < 27) v = w_mod[((oc - 18) * 128 + c) * 9 + tap];
    wOM[e] = f2bf(v);
  } else {                                // --- wAs pack (wave-swizzled) ---
    int e = (blk - 2192) * 256 + t;       // tap*16384 + oc*128 + c
    int tap = e >> 14, oc = (e >> 7) & 127, c = e & 127;
    int kb = c >> 5, quad = (c >> 3) & 3, j = c & 7;
    int g = oc >> 4, l16 = oc & 15;
    int o = ((tap * 4 + kb) * 8 + g) * 512 + (quad * 16 + l16) * 8 + j;
    wAs[o] = f2bf(w_reg[(oc * 128 + c) * 9 + tap]);
  }
}

// ---------------------------------------------------------------------------
// Kernel 2: offset+mask conv as bf16 MFMA GEMM + fused pym epilogue.
// XCD swizzle: b = blk&7 so each XCD keeps one image's xbh in L2.
// ---------------------------------------------------------------------------
__global__ __launch_bounds__(256) void k_offmask(const short* __restrict__ xbh,
    const short* __restrict__ wOM, const float* __restrict__ b_off,
    const float* __restrict__ b_mod, float4* __restrict__ pym) {
  __shared__ __align__(16) short wa_s[32 * OAP];
  __shared__ __align__(16) short vs[128 * OAP];
  __shared__ float sc[32 * 132];

  int blk = blockIdx.x;
  int b = blk & 7, tile = blk >> 3;
  int pix0 = tile * 128;
  int t = threadIdx.x;
  int lane = t & 63, wv = t >> 6;
  int l16 = lane & 15, quad = lane >> 4;
  int cg = t & 15, pj = t >> 4;

  const short* xbb = xbh + (size_t)b * NPIX * CIN;
  f32x4 acc[2][2] = {};

  for (int tap = 0; tap < 9; ++tap) {
    __syncthreads();
    {
      const float4* src = (const float4*)(wOM + tap * 4096);
#pragma unroll
      for (int j = 0; j < 2; ++j) {
        int e = t + j * 256;
        int oc = e >> 4, seg = e & 15;
        *(float4*)&wa_s[oc * OAP + seg * 8] = src[e];
      }
    }
    int dy = tap / 3 - 1, dx = tap % 3 - 1;
#pragma unroll
    for (int i = 0; i < 8; ++i) {
      int p = pj + i * 16;
      int gp = pix0 + p;
      int y = (gp >> 6) + dy, x = (gp & 63) + dx;
      bf16x8 v = {};
      if (y >= 0 && y < H && x >= 0 && x < W)
        v = *(const bf16x8*)&xbb[(size_t)((y << 6) + x) * CIN + cg * 8];
      *(bf16x8*)&vs[p * OAP + cg * 8] = v;
    }
    __syncthreads();
#pragma unroll
    for (int kb = 0; kb < 4; ++kb) {
      int kcol = kb * 32 + quad * 8;
      bf16x8 a0 = *(const bf16x8*)&wa_s[l16 * OAP + kcol];
      bf16x8 a1 = *(const bf16x8*)&wa_s[(16 + l16) * OAP + kcol];
      bf16x8 b0 = *(const bf16x8*)&vs[(wv * 32 + l16) * OAP + kcol];
      bf16x8 b1 = *(const bf16x8*)&vs[(wv * 32 + 16 + l16) * OAP + kcol];
      acc[0][0] = __builtin_amdgcn_mfma_f32_16x16x32_bf16(a0, b0, acc[0][0], 0, 0, 0);
      acc[0][1] = __builtin_amdgcn_mfma_f32_16x16x32_bf16(a0, b1, acc[0][1], 0, 0, 0);
      acc[1][0] = __builtin_amdgcn_mfma_f32_16x16x32_bf16(a1, b0, acc[1][0], 0, 0, 0);
      acc[1][1] = __builtin_amdgcn_mfma_f32_16x16x32_bf16(a1, b1, acc[1][1], 0, 0, 0);
    }
  }
  __syncthreads();
#pragma unroll
  for (int mt = 0; mt < 2; ++mt)
#pragma unroll
    for (int nt = 0; nt < 2; ++nt)
#pragma unroll
      for (int r = 0; r < 4; ++r) {
        int oc = mt * 16 + quad * 4 + r;
        int p  = wv * 32 + nt * 16 + l16;
        sc[oc * 132 + p] = acc[mt][nt][r];
      }
  __syncthreads();
  for (int i = t; i < 128 * 9; i += 256) {
    int tap = i % 9, p = i / 9;
    float dyv = sc[(2 * tap) * 132 + p] + b_off[2 * tap];
    float dxv = sc[(2 * tap + 1) * 132 + p] + b_off[2 * tap + 1];
    float z   = sc[(18 + tap) * 132 + p] + b_mod[tap];
    float m = 2.f / (1.f + expf(-z));
    int gp = pix0 + p;
    float py = (float)((gp >> 6) - 1 + tap / 3) + dyv;
    float px = (float)((gp & 63) - 1 + tap % 3) + dxv;
    pym[(size_t)(b * NPIX + gp) * 9 + tap] = make_float4(py, px, m, 0.f);
  }
}

// ---------------------------------------------------------------------------
// Kernel 3: main deformable conv, bf16 MFMA GEMM.
// R6: (1) XCD swizzle b=blk&7 (one fp32 image + wAs per XCD L2);
// (2) float2 channel-pair sampling (half the VMEM instrs) + packed
// v_cvt_pk_bf16_f32 LDS writes.
// ---------------------------------------------------------------------------
__global__ __launch_bounds__(256) void k_deform(const float* __restrict__ xb,
    const float4* __restrict__ pym, const short* __restrict__ wAs,
    float* __restrict__ out) {
  __shared__ __align__(16) short vs[PXT * AP];    //  8704 B
  __shared__ __align__(16) float pw[PXT * 9 * 4]; //  4608 B {w00,w01,w10,w11}
  __shared__ __align__(16) int   pa[PXT * 9 * 4]; //  4608 B {a00,a01,a10,a11}

  int blk = blockIdx.x;
  int b = blk & 7, tile = blk >> 3;
  int pix0 = tile * PXT;
  int t = threadIdx.x;
  int lane = t & 63;
  int wv = t >> 6;
  int l16 = lane & 15, quad = lane >> 4;

  // --- per-(px,tap) precompute: 288 entries, once per block ---
  for (int i = t; i < PXT * 9; i += 256) {
    float4 q = pym[(size_t)(b * NPIX + pix0 + i / 9) * 9 + (i % 9)];
    float py = q.x, pxx = q.y, m = q.z;
    float yf = floorf(py), xf = floorf(pxx);
    float wy = py - yf, wx = pxx - xf;
    int y0 = (int)yf, x0 = (int)xf;
    int y1 = y0 + 1, x1 = x0 + 1;
    float vy0 = (y0 >= 0 && y0 < H) ? 1.f : 0.f;
    float vy1 = (y1 >= 0 && y1 < H) ? 1.f : 0.f;
    float vx0 = (x0 >= 0 && x0 < W) ? 1.f : 0.f;
    float vx1 = (x1 >= 0 && x1 < W) ? 1.f : 0.f;
    int y0c = min(max(y0, 0), H - 1), y1c = min(max(y1, 0), H - 1);
    int x0c = min(max(x0, 0), W - 1), x1c = min(max(x1, 0), W - 1);
    *(float4*)&pw[i * 4] = make_float4((1.f - wy) * (1.f - wx) * m * vy0 * vx0,
                                       (1.f - wy) * wx * m * vy0 * vx1,
                                       wy * (1.f - wx) * m * vy1 * vx0,
                                       wy * wx * m * vy1 * vx1);
    *(int4*)&pa[i * 4] = make_int4(((y0c << 6) + x0c) << 7,
                                   ((y0c << 6) + x1c) << 7,
                                   ((y1c << 6) + x0c) << 7,
                                   ((y1c << 6) + x1c) << 7);
  }

  int cp = t & 63, grp = t >> 6;          // channel pair, pixel group
  int c0 = cp * 2;
  const float* xbB = xb + (size_t)b * NPIX * CIN;

  f32x4 acc[2][2] = {};

  for (int tap = 0; tap < 9; ++tap) {
    __syncthreads();   // prev tap's vs consumed (tap0: pw/pa visible)

    // --- sample B tile: 8 px x 2 ch per thread; p wave-uniform (grp=wave) ---
#pragma unroll
    for (int i = 0; i < 8; ++i) {
      int p = grp * 8 + i;
      int idx = (p * 9 + tap) * 4;
      float4 wq = *(const float4*)&pw[idx];
      int a00 = __builtin_amdgcn_readfirstlane(pa[idx]);
      int a01 = __builtin_amdgcn_readfirstlane(pa[idx + 1]);
      int a10 = __builtin_amdgcn_readfirstlane(pa[idx + 2]);
      int a11 = __builtin_amdgcn_readfirstlane(pa[idx + 3]);
      float2 v00 = *(const float2*)&xbB[a00 + c0];
      float2 v01 = *(const float2*)&xbB[a01 + c0];
      float2 v10 = *(const float2*)&xbB[a10 + c0];
      float2 v11 = *(const float2*)&xbB[a11 + c0];
      float s0 = wq.x * v00.x;
      float s1 = wq.x * v00.y;
      s0 = fmaf(wq.y, v01.x, s0); s1 = fmaf(wq.y, v01.y, s1);
      s0 = fmaf(wq.z, v10.x, s0); s1 = fmaf(wq.z, v10.y, s1);
      s0 = fmaf(wq.w, v11.x, s0); s1 = fmaf(wq.w, v11.y, s1);
      __hip_bfloat162 h2 = __float22bfloat162_rn(make_float2(s0, s1));
      *(unsigned int*)&vs[p * AP + c0] = *(unsigned int*)&h2;
    }

    // --- A frags direct from global (contiguous 1 KB per wave-load) ---
    const short* wtap = wAs + tap * 16384;
    bf16x8 af0[4], af1[4];
#pragma unroll
    for (int kb = 0; kb < 4; ++kb) {
      af0[kb] = *(const bf16x8*)&wtap[(kb * 8 + wv * 2) * 512 + lane * 8];
      af1[kb] = *(const bf16x8*)&wtap[(kb * 8 + wv * 2 + 1) * 512 + lane * 8];
    }
    __syncthreads();

#pragma unroll
    for (int kb = 0; kb < 4; ++kb) {
      int kcol = kb * 32 + quad * 8;
      bf16x8 b0 = *(const bf16x8*)&vs[l16 * AP + kcol];
      bf16x8 b1 = *(const bf16x8*)&vs[(16 + l16) * AP + kcol];
      acc[0][0] = __builtin_amdgcn_mfma_f32_16x16x32_bf16(af0[kb], b0, acc[0][0], 0, 0, 0);
      acc[0][1] = __builtin_amdgcn_mfma_f32_16x16x32_bf16(af0[kb], b1, acc[0][1], 0, 0, 0);
      acc[1][0] = __builtin_amdgcn_mfma_f32_16x16x32_bf16(af1[kb], b0, acc[1][0], 0, 0, 0);
      acc[1][1] = __builtin_amdgcn_mfma_f32_16x16x32_bf16(af1[kb], b1, acc[1][1], 0, 0, 0);
    }
  }

  // --- epilogue: D[m=quad*4+r][n=l16] -> out[b][oc][pix] ---
  int oc_off = wv * 32;
#pragma unroll
  for (int mt = 0; mt < 2; ++mt)
#pragma unroll
    for (int nt = 0; nt < 2; ++nt)
#pragma unroll
      for (int r = 0; r < 4; ++r) {
        int oc = oc_off + mt * 16 + quad * 4 + r;
        int px = nt * 16 + l16;
        out[(size_t)(b * COUT + oc) * NPIX + pix0 + px] = acc[mt][nt][r];
      }
}

// ---------------------------------------------------------------------------
extern "C" void kernel_launch(void* const* d_in, const int* in_sizes, int n_in,
                              void* d_out, int out_size, void* d_ws, size_t ws_size,
                              hipStream_t stream) {
  const float* x     = (const float*)d_in[0];
  const float* w_off = (const float*)d_in[1];
  const float* b_off = (const float*)d_in[2];
  const float* w_mod = (const float*)d_in[3];
  const float* b_mod = (const float*)d_in[4];
  const float* w_reg = (const float*)d_in[5];

  float* ws   = (float*)d_ws;
  float* xb   = ws;                        // 4,194,304 f32
  float* pym  = xb + 4194304;              // 1,179,648 f32 (float4 entries)
  short* wAs  = (short*)(pym + 1179648);   //   147,456 bf16 (swizzled)
  short* xbh  = wAs + 147456;              // 4,194,304 bf16
  short* wOM  = xbh + 4194304;             //    36,864 bf16
  float* out  = (float*)d_out;

  k_prep<<<dim3(2768), 256, 0, stream>>>(x, xb, xbh, w_off, w_mod, wOM,
                                         w_reg, wAs);
  k_offmask<<<dim3(256), 256, 0, stream>>>(
      xbh, wOM, b_off, b_mod, (float4*)pym);
  k_deform<<<dim3(NPIX / PXT * BATCH), 256, 0, stream>>>(
      xb, (const float4*)pym, wAs, out);
}

// Round 7
// 130.849 us; speedup vs baseline: 7.1471x; 1.1279x over previous
//
#include <hip/hip_runtime.h>
#include <hip/hip_bf16.h>
#include <math.h>

#define H 64
#define W 64
#define CIN 128
#define COUT 128
#define BATCH 8
#define NPIX (H*W)      // 4096
#define PXT 32          // pixels per k_deform block
#define AP  136         // padded LDS pitch in bf16 elems (16B-aligned rows)
#define OAP 136

typedef __attribute__((ext_vector_type(8))) short bf16x8;
typedef __attribute__((ext_vector_type(4))) float f32x4;

static __device__ inline short f2bf(float f) {
  union { float f; unsigned u; } v; v.f = f;
  unsigned r = v.u + 0x7FFF + ((v.u >> 16) & 1);   // RNE
  return (short)(r >> 16);
}
static __device__ inline float bf_lo(unsigned u) {
  union { unsigned u; float f; } v; v.u = u << 16; return v.f;
}
static __device__ inline float bf_hi(unsigned u) {
  union { unsigned u; float f; } v; v.u = u & 0xffff0000u; return v.f;
}

// ---------------------------------------------------------------------------
// Kernel 1 (fused prep): [0,2048) transpose NCHW->BHWC bf16;
// [2048,2192) pack wOM; [2192,2768) pack swizzled wAs.
// ---------------------------------------------------------------------------
__global__ __launch_bounds__(256) void k_prep(const float* __restrict__ x,
    short* __restrict__ xbh,
    const float* __restrict__ w_off, const float* __restrict__ w_mod,
    short* __restrict__ wOM, const float* __restrict__ w_reg,
    short* __restrict__ wAs) {
  __shared__ float tile[32][65];
  int blk = blockIdx.x;
  int t = threadIdx.x;
  if (blk < 2048) {                       // --- transpose ---
    int cg = blk & 3, y = (blk >> 2) & 63, b = blk >> 8;
#pragma unroll
    for (int j = 0; j < 8; ++j) {
      int idx = t + j * 256;
      int ci = idx >> 6, xi = idx & 63;
      tile[ci][xi] = x[(((b * CIN + cg * 32 + ci) * H + y) * W) + xi];
    }
    __syncthreads();
#pragma unroll
    for (int j = 0; j < 8; ++j) {
      int idx = t + j * 256;
      int xi = idx >> 5, ci = idx & 31;
      xbh[((b * H + y) * W + xi) * CIN + cg * 32 + ci] = f2bf(tile[ci][xi]);
    }
  } else if (blk < 2048 + 144) {          // --- wOM pack ---
    int e = (blk - 2048) * 256 + t;       // tap*4096 + oc*128 + c
    int tap = e >> 12, oc = (e >> 7) & 31, c = e & 127;
    float v = 0.f;
    if (oc < 18)      v = w_off[(oc * 128 + c) * 9 + tap];
    else if (oc < 27) v = w_mod[((oc - 18) * 128 + c) * 9 + tap];
    wOM[e] = f2bf(v);
  } else {                                // --- wAs pack (wave-swizzled) ---
    int e = (blk - 2192) * 256 + t;       // tap*16384 + oc*128 + c
    int tap = e >> 14, oc = (e >> 7) & 127, c = e & 127;
    int kb = c >> 5, quad = (c >> 3) & 3, j = c & 7;
    int g = oc >> 4, l16 = oc & 15;
    int o = ((tap * 4 + kb) * 8 + g) * 512 + (quad * 16 + l16) * 8 + j;
    wAs[o] = f2bf(w_reg[(oc * 128 + c) * 9 + tap]);
  }
}

// ---------------------------------------------------------------------------
// Kernel 2: offset+mask conv, bf16 MFMA GEMM + fused pym epilogue.
// R7: 64-px tiles -> grid 512 (2x wave parallelism), XCD swizzle b=blk&7.
// Wave wv: M=32 oc x N=16 px slice [wv*16, wv*16+16).
// ---------------------------------------------------------------------------
__global__ __launch_bounds__(256) void k_offmask(const short* __restrict__ xbh,
    const short* __restrict__ wOM, const float* __restrict__ b_off,
    const float* __restrict__ b_mod, float4* __restrict__ pym) {
  __shared__ __align__(16) short wa_s[32 * OAP];   //  8.7 KB
  __shared__ __align__(16) short vs[64 * OAP];     // 17.4 KB
  __shared__ float sc[32 * 68];                    //  8.7 KB

  int blk = blockIdx.x;
  int b = blk & 7, tile = blk >> 3;
  int pix0 = tile * 64;
  int t = threadIdx.x;
  int lane = t & 63, wv = t >> 6;
  int l16 = lane & 15, quad = lane >> 4;
  int cg = t & 15, pj = t >> 4;          // B-stage: 16 chunks x 16 px-groups

  const short* xbb = xbh + (size_t)b * NPIX * CIN;
  f32x4 acc2[2] = {};

  for (int tap = 0; tap < 9; ++tap) {
    __syncthreads();
    {
      const float4* src = (const float4*)(wOM + tap * 4096);
#pragma unroll
      for (int j = 0; j < 2; ++j) {
        int e = t + j * 256;
        int oc = e >> 4, seg = e & 15;
        *(float4*)&wa_s[oc * OAP + seg * 8] = src[e];
      }
    }
    int dy = tap / 3 - 1, dx = tap % 3 - 1;
#pragma unroll
    for (int i = 0; i < 4; ++i) {
      int p = pj + i * 16;
      int gp = pix0 + p;
      int y = (gp >> 6) + dy, x = (gp & 63) + dx;
      bf16x8 v = {};
      if (y >= 0 && y < H && x >= 0 && x < W)
        v = *(const bf16x8*)&xbb[(size_t)((y << 6) + x) * CIN + cg * 8];
      *(bf16x8*)&vs[p * OAP + cg * 8] = v;
    }
    __syncthreads();
#pragma unroll
    for (int kb = 0; kb < 4; ++kb) {
      int kcol = kb * 32 + quad * 8;
      bf16x8 a0 = *(const bf16x8*)&wa_s[l16 * OAP + kcol];
      bf16x8 a1 = *(const bf16x8*)&wa_s[(16 + l16) * OAP + kcol];
      bf16x8 b0 = *(const bf16x8*)&vs[(wv * 16 + l16) * OAP + kcol];
      acc2[0] = __builtin_amdgcn_mfma_f32_16x16x32_bf16(a0, b0, acc2[0], 0, 0, 0);
      acc2[1] = __builtin_amdgcn_mfma_f32_16x16x32_bf16(a1, b0, acc2[1], 0, 0, 0);
    }
  }
  __syncthreads();
#pragma unroll
  for (int mt = 0; mt < 2; ++mt)
#pragma unroll
    for (int r = 0; r < 4; ++r) {
      int oc = mt * 16 + quad * 4 + r;
      int p  = wv * 16 + l16;
      sc[oc * 68 + p] = acc2[mt][r];
    }
  __syncthreads();
  for (int i = t; i < 64 * 9; i += 256) {
    int tap = i % 9, p = i / 9;
    float dyv = sc[(2 * tap) * 68 + p] + b_off[2 * tap];
    float dxv = sc[(2 * tap + 1) * 68 + p] + b_off[2 * tap + 1];
    float z   = sc[(18 + tap) * 68 + p] + b_mod[tap];
    float m = 2.f / (1.f + expf(-z));
    int gp = pix0 + p;
    float py = (float)((gp >> 6) - 1 + tap / 3) + dyv;
    float px = (float)((gp & 63) - 1 + tap % 3) + dxv;
    pym[(size_t)(b * NPIX + gp) * 9 + tap] = make_float4(py, px, m, 0.f);
  }
}

// ---------------------------------------------------------------------------
// Kernel 3: main deformable conv, bf16 MFMA GEMM.
// R7: 512 threads / 8 waves (wave = (oc-slice ms, px-half nh));
// sampling from bf16 xbh as bf16x4 (4ch, 8B) — half the L2 bytes & instrs.
// Lane layout (sampling): cq = t&31 -> 4 ch; pxsub = (t>>5)&1; grp = t>>6.
// ---------------------------------------------------------------------------
__global__ __launch_bounds__(512) void k_deform(const short* __restrict__ xbh,
    const float4* __restrict__ pym, const short* __restrict__ wAs,
    float* __restrict__ out) {
  __shared__ __align__(16) short vs[PXT * AP];    //  8.7 KB
  __shared__ __align__(16) float pw[PXT * 9 * 4]; //  4.6 KB {w00,w01,w10,w11}
  __shared__ __align__(16) int   pa[PXT * 9 * 4]; //  4.6 KB {a00,a01,a10,a11}

  int blk = blockIdx.x;
  int b = blk & 7, tile = blk >> 3;
  int pix0 = tile * PXT;
  int t = threadIdx.x;
  int lane = t & 63;
  int wv = t >> 6;                        // 0..7
  int ms = wv & 3, nh = wv >> 2;          // oc-slice, px-half
  int l16 = lane & 15, quad = lane >> 4;

  // --- per-(px,tap) precompute: 288 entries, once per block ---
  for (int i = t; i < PXT * 9; i += 512) {
    float4 q = pym[(size_t)(b * NPIX + pix0 + i / 9) * 9 + (i % 9)];
    float py = q.x, pxx = q.y, m = q.z;
    float yf = floorf(py), xf = floorf(pxx);
    float wy = py - yf, wx = pxx - xf;
    int y0 = (int)yf, x0 = (int)xf;
    int y1 = y0 + 1, x1 = x0 + 1;
    float vy0 = (y0 >= 0 && y0 < H) ? 1.f : 0.f;
    float vy1 = (y1 >= 0 && y1 < H) ? 1.f : 0.f;
    float vx0 = (x0 >= 0 && x0 < W) ? 1.f : 0.f;
    float vx1 = (x1 >= 0 && x1 < W) ? 1.f : 0.f;
    int y0c = min(max(y0, 0), H - 1), y1c = min(max(y1, 0), H - 1);
    int x0c = min(max(x0, 0), W - 1), x1c = min(max(x1, 0), W - 1);
    *(float4*)&pw[i * 4] = make_float4((1.f - wy) * (1.f - wx) * m * vy0 * vx0,
                                       (1.f - wy) * wx * m * vy0 * vx1,
                                       wy * (1.f - wx) * m * vy1 * vx0,
                                       wy * wx * m * vy1 * vx1);
    *(int4*)&pa[i * 4] = make_int4(((y0c << 6) + x0c) << 7,
                                   ((y0c << 6) + x1c) << 7,
                                   ((y1c << 6) + x0c) << 7,
                                   ((y1c << 6) + x1c) << 7);
  }

  int cq = t & 31, pxsub = (t >> 5) & 1, grp = t >> 6;
  int c0 = cq * 4;
  const short* xbB = xbh + (size_t)b * NPIX * CIN;

  f32x4 acc[2] = {};

  for (int tap = 0; tap < 9; ++tap) {
    __syncthreads();   // prev tap's vs consumed (tap0: pw/pa visible)

    // --- A frags (prefetch; in flight during sampling) ---
    const short* wtap = wAs + tap * 16384;
    bf16x8 af0[4], af1[4];
#pragma unroll
    for (int kb = 0; kb < 4; ++kb) {
      af0[kb] = *(const bf16x8*)&wtap[(kb * 8 + ms * 2) * 512 + lane * 8];
      af1[kb] = *(const bf16x8*)&wtap[(kb * 8 + ms * 2 + 1) * 512 + lane * 8];
    }

    // --- sample B tile: 2 iters x (4 corners x 4 ch) per thread ---
#pragma unroll
    for (int i = 0; i < 2; ++i) {
      int p = grp * 4 + i * 2 + pxsub;
      int idx = (p * 9 + tap) * 4;
      float4 wq = *(const float4*)&pw[idx];
      int4 aa = *(const int4*)&pa[idx];
      uint2 u00 = *(const uint2*)&xbB[aa.x + c0];
      uint2 u01 = *(const uint2*)&xbB[aa.y + c0];
      uint2 u10 = *(const uint2*)&xbB[aa.z + c0];
      uint2 u11 = *(const uint2*)&xbB[aa.w + c0];
      float s0 = wq.x * bf_lo(u00.x), s1 = wq.x * bf_hi(u00.x);
      float s2 = wq.x * bf_lo(u00.y), s3 = wq.x * bf_hi(u00.y);
      s0 = fmaf(wq.y, bf_lo(u01.x), s0); s1 = fmaf(wq.y, bf_hi(u01.x), s1);
      s2 = fmaf(wq.y, bf_lo(u01.y), s2); s3 = fmaf(wq.y, bf_hi(u01.y), s3);
      s0 = fmaf(wq.z, bf_lo(u10.x), s0); s1 = fmaf(wq.z, bf_hi(u10.x), s1);
      s2 = fmaf(wq.z, bf_lo(u10.y), s2); s3 = fmaf(wq.z, bf_hi(u10.y), s3);
      s0 = fmaf(wq.w, bf_lo(u11.x), s0); s1 = fmaf(wq.w, bf_hi(u11.x), s1);
      s2 = fmaf(wq.w, bf_lo(u11.y), s2); s3 = fmaf(wq.w, bf_hi(u11.y), s3);
      __hip_bfloat162 h2a = __float22bfloat162_rn(make_float2(s0, s1));
      __hip_bfloat162 h2b = __float22bfloat162_rn(make_float2(s2, s3));
      uint2 packed;
      packed.x = *(unsigned*)&h2a;
      packed.y = *(unsigned*)&h2b;
      *(uint2*)&vs[p * AP + c0] = packed;
    }
    __syncthreads();

    // --- MFMA: 4 k-steps, 2 m-tiles x 1 n-tile per wave ---
#pragma unroll
    for (int kb = 0; kb < 4; ++kb) {
      int kcol = kb * 32 + quad * 8;
      bf16x8 b0 = *(const bf16x8*)&vs[(nh * 16 + l16) * AP + kcol];
      acc[0] = __builtin_amdgcn_mfma_f32_16x16x32_bf16(af0[kb], b0, acc[0], 0, 0, 0);
      acc[1] = __builtin_amdgcn_mfma_f32_16x16x32_bf16(af1[kb], b0, acc[1], 0, 0, 0);
    }
  }

  // --- epilogue: D[m=quad*4+r][n=l16] -> out[b][oc][pix] ---
  int oc_base = ms * 32;
#pragma unroll
  for (int mt = 0; mt < 2; ++mt)
#pragma unroll
    for (int r = 0; r < 4; ++r) {
      int oc = oc_base + mt * 16 + quad * 4 + r;
      int px = nh * 16 + l16;
      out[(size_t)(b * COUT + oc) * NPIX + pix0 + px] = acc[mt][r];
    }
}

// ---------------------------------------------------------------------------
extern "C" void kernel_launch(void* const* d_in, const int* in_sizes, int n_in,
                              void* d_out, int out_size, void* d_ws, size_t ws_size,
                              hipStream_t stream) {
  const float* x     = (const float*)d_in[0];
  const float* w_off = (const float*)d_in[1];
  const float* b_off = (const float*)d_in[2];
  const float* w_mod = (const float*)d_in[3];
  const float* b_mod = (const float*)d_in[4];
  const float* w_reg = (const float*)d_in[5];

  short* xbh  = (short*)d_ws;              // 4,194,304 bf16 (8 MB)
  float* pym  = (float*)(xbh + 4194304);   // 1,179,648 f32 (float4 entries)
  short* wAs  = (short*)(pym + 1179648);   //   147,456 bf16 (swizzled)
  short* wOM  = wAs + 147456;              //    36,864 bf16
  float* out  = (float*)d_out;

  k_prep<<<dim3(2768), 256, 0, stream>>>(x, xbh, w_off, w_mod, wOM,
                                         w_reg, wAs);
  k_offmask<<<dim3(512), 256, 0, stream>>>(
      xbh, wOM, b_off, b_mod, (float4*)pym);
  k_deform<<<dim3(NPIX / PXT * BATCH), 512, 0, stream>>>(
      xbh, (const float4*)pym, wAs, out);
}